// Round 1
// baseline (23843.761 us; speedup 1.0000x reference)
//
#include <hip/hip_runtime.h>
#include <hip/hip_bf16.h>

#define T_STEPS 2048
#define BATCH 16
#define INF 72
#define HID 256
#define OUTF 90

typedef __attribute__((ext_vector_type(4))) float f32x4;
typedef __attribute__((ext_vector_type(8))) short s16x8;

__device__ __forceinline__ unsigned short f2bf(float f) {
  union { float f; unsigned u; } v; v.f = f;
  unsigned r = (v.u + 0x7FFFu + ((v.u >> 16) & 1u)) >> 16;   // RNE
  return (unsigned short)r;
}
__device__ __forceinline__ float sigm(float x) { return 1.f / (1.f + __expf(-x)); }
__device__ __forceinline__ float tanh_f(float x) { return 1.f - 2.f / (1.f + __expf(2.f * x)); }

// ---------------- input projection: h0 = relu(x @ W1^T + b1) ----------------
__global__ __launch_bounds__(256) void inproj(const float* __restrict__ x,
                                              const float* __restrict__ W1,
                                              const float* __restrict__ b1,
                                              float* __restrict__ h0) {
  __shared__ float w1s[HID][INF + 1];   // +1 pad: stride 73 -> conflict-free
  __shared__ float xs[16][INF];
  const int tid = threadIdx.x;
  const int r0 = blockIdx.x * 16;
  for (int i = tid; i < HID * INF; i += 256) w1s[i / INF][i % INF] = W1[i];
  for (int i = tid; i < 16 * INF; i += 256)
    xs[i / INF][i % INF] = x[(size_t)(r0 + i / INF) * INF + (i % INF)];
  __syncthreads();
  const float bj = b1[tid];
  for (int r = 0; r < 16; ++r) {
    float acc = bj;
#pragma unroll 8
    for (int k = 0; k < INF; ++k) acc += xs[r][k] * w1s[tid][k];
    h0[(size_t)(r0 + r) * HID + tid] = fmaxf(acc, 0.f);
  }
}

// ------------- gi GEMM: C[32768][1024] = A[32768][256] @ B[1024][256]^T -------------
// BM=128 BN=64 BK=16, 256 threads, thread tile 8x4
__global__ __launch_bounds__(256) void gemm_nt(const float* __restrict__ A,
                                               const float* __restrict__ B,
                                               float* __restrict__ C) {
  const int K = 256, N = 1024;
  __shared__ __align__(16) float As[16][132];
  __shared__ __align__(16) float Bs[16][68];
  const int tid = threadIdx.x;
  const int bm = blockIdx.x, bn = blockIdx.y;
  const int tr = tid >> 4, tc = tid & 15;
  const int arow = tid >> 1, acol = (tid & 1) * 8;
  const int brow = tid >> 2, bcol = (tid & 3) * 4;
  float acc[8][4] = {};
  for (int k0 = 0; k0 < K; k0 += 16) {
    f32x4 av0 = *(const f32x4*)&A[(size_t)(bm * 128 + arow) * K + k0 + acol];
    f32x4 av1 = *(const f32x4*)&A[(size_t)(bm * 128 + arow) * K + k0 + acol + 4];
    f32x4 bv  = *(const f32x4*)&B[(size_t)(bn * 64 + brow) * K + k0 + bcol];
#pragma unroll
    for (int e = 0; e < 4; ++e) {
      As[acol + e][arow] = av0[e];
      As[acol + 4 + e][arow] = av1[e];
      Bs[bcol + e][brow] = bv[e];
    }
    __syncthreads();
#pragma unroll
    for (int kk = 0; kk < 16; ++kk) {
      f32x4 a0 = *(const f32x4*)&As[kk][tr * 8];
      f32x4 a1 = *(const f32x4*)&As[kk][tr * 8 + 4];
      f32x4 b  = *(const f32x4*)&Bs[kk][tc * 4];
#pragma unroll
      for (int i = 0; i < 4; ++i)
#pragma unroll
        for (int jj = 0; jj < 4; ++jj) {
          acc[i][jj]     += a0[i] * b[jj];
          acc[i + 4][jj] += a1[i] * b[jj];
        }
    }
    __syncthreads();
  }
#pragma unroll
  for (int i = 0; i < 8; ++i) {
    f32x4 v;
#pragma unroll
    for (int jj = 0; jj < 4; ++jj) v[jj] = acc[i][jj];
    *(f32x4*)&C[(size_t)(bm * 128 + tr * 8 + i) * N + bn * 64 + tc * 4] = v;
  }
}

// ---------------- the serial LSTM scan: 2 WGs, Whh resident in VGPRs as bf16 ----------------
// WG g owns hidden units [g*128, g*128+128); wave w owns 16 units; each lane holds the
// i,f,g,o gate values for (4 batches x 1 unit) -> gate math is lane-local.
__global__ __launch_bounds__(512, 2) void lstm_scan(
    const float* __restrict__ gi,    // [T][B][4H]
    const float* __restrict__ Whh,   // [4H][H]
    const float* __restrict__ bih, const float* __restrict__ bhh,  // [4H]
    const int* __restrict__ lengths, // [B]
    float* __restrict__ hout,        // [T][B][H]  (masked-zero ys)
    float* hx,                       // [2][B][H]  exchange (zeroed at launch)
    unsigned int* cnt)               // monotonic barrier counter (zeroed at launch)
{
  const int tid  = threadIdx.x;
  const int lane = tid & 63;
  const int wid  = tid >> 6;         // 0..7
  const int grp  = blockIdx.x;       // 0..1
  const int j    = lane & 15;
  const int hi   = lane >> 4;        // 0..3
  const int u    = grp * 128 + wid * 16 + j;   // this lane's hidden unit

  // B-fragments: Whh rows for gates q at unit u; lane k-range = (lane>>4)*8 within K-tile
  s16x8 bfr[4][8];
#pragma unroll
  for (int q = 0; q < 4; ++q)
#pragma unroll
    for (int kt = 0; kt < 8; ++kt) {
      const float* wrow = Whh + (size_t)(q * 256 + u) * 256 + kt * 32 + hi * 8;
      s16x8 v;
#pragma unroll
      for (int e = 0; e < 8; ++e) v[e] = (short)f2bf(wrow[e]);
      bfr[q][kt] = v;
    }
  float bias[4];
#pragma unroll
  for (int q = 0; q < 4; ++q) bias[q] = bih[q * 256 + u] + bhh[q * 256 + u];
  int len[4];
#pragma unroll
  for (int r = 0; r < 4; ++r) len[r] = lengths[hi * 4 + r];
  float c[4] = {0.f, 0.f, 0.f, 0.f}, hprev[4] = {0.f, 0.f, 0.f, 0.f};

  __shared__ __align__(16) unsigned short hlds[16 * 256];  // bf16 h, XOR-swizzled
  const int xb = tid >> 5;           // staging: this thread's batch row
  const int xk = (tid & 31) * 8;     // and k-range (8 floats)

  for (int t = 0; t < T_STEPS; ++t) {
    // prefetch gi[t] before the spin (independent of the barrier)
    float gval[4][4];
#pragma unroll
    for (int q = 0; q < 4; ++q)
#pragma unroll
      for (int r = 0; r < 4; ++r)
        gval[q][r] = gi[((size_t)t * BATCH + hi * 4 + r) * 1024 + q * 256 + u];

    if (t > 0) {
      const unsigned target = 2u * (unsigned)t;
      while (__hip_atomic_load(cnt, __ATOMIC_ACQUIRE, __HIP_MEMORY_SCOPE_AGENT) < target)
        __builtin_amdgcn_s_sleep(2);
    }

    // stage full h (both WGs' halves) from exchange buffer into LDS as bf16, swizzled
    {
      const float* src = hx + (size_t)(t & 1) * 4096 + xb * 256 + xk;
      s16x8 v;
#pragma unroll
      for (int e = 0; e < 8; ++e) {
        float f = __hip_atomic_load(src + e, __ATOMIC_RELAXED, __HIP_MEMORY_SCOPE_AGENT);
        v[e] = (short)f2bf(f);
      }
      const int off = ((xb << 9) + (xk << 1)) ^ ((xb & 7) << 4);
      *(s16x8*)((char*)hlds + off) = v;
    }
    __syncthreads();

    // A-fragments from LDS + MFMA accumulate: g_tile = h @ Whh_slice^T
    f32x4 acc[4] = {{0.f,0.f,0.f,0.f},{0.f,0.f,0.f,0.f},{0.f,0.f,0.f,0.f},{0.f,0.f,0.f,0.f}};
#pragma unroll
    for (int kt = 0; kt < 8; ++kt) {
      const int k = kt * 32 + hi * 8;
      const int off = ((j << 9) + (k << 1)) ^ ((j & 7) << 4);
      const s16x8 a = *(const s16x8*)((const char*)hlds + off);
#pragma unroll
      for (int q = 0; q < 4; ++q)
        acc[q] = __builtin_amdgcn_mfma_f32_16x16x32_bf16(a, bfr[q][kt], acc[q], 0, 0, 0);
    }

    // gates + state update (lane-local), stores
#pragma unroll
    for (int r = 0; r < 4; ++r) {
      const float g0 = acc[0][r] + gval[0][r] + bias[0];
      const float g1 = acc[1][r] + gval[1][r] + bias[1];
      const float g2 = acc[2][r] + gval[2][r] + bias[2];
      const float g3 = acc[3][r] + gval[3][r] + bias[3];
      const float i_ = sigm(g0), f_ = sigm(g1), tg = tanh_f(g2), o_ = sigm(g3);
      const float cn = f_ * c[r] + i_ * tg;
      const float hn = o_ * tanh_f(cn);
      const bool  m  = t < len[r];
      c[r] = m ? cn : c[r];
      const float hk = m ? hn : hprev[r];
      hprev[r] = hk;
      const int b = hi * 4 + r;
      hout[((size_t)t * BATCH + b) * HID + u] = m ? hn : 0.f;
      __hip_atomic_store(hx + (size_t)((t + 1) & 1) * 4096 + b * 256 + u, hk,
                         __ATOMIC_RELAXED, __HIP_MEMORY_SCOPE_AGENT);
    }
    __syncthreads();   // drains vmcnt -> all agent-scope stores globally visible
    if (tid == 0)
      __hip_atomic_fetch_add(cnt, 1u, __ATOMIC_RELEASE, __HIP_MEMORY_SCOPE_AGENT);
  }
}

// ---------------- output projection: y = mask ? h2 @ W2^T + b2 : 0 ----------------
__global__ __launch_bounds__(256) void outproj(const float* __restrict__ h2,
                                               const float* __restrict__ W2,
                                               const float* __restrict__ b2,
                                               const int* __restrict__ lengths,
                                               float* __restrict__ y) {
  __shared__ float w2s[OUTF][HID + 1];
  __shared__ float hs[8][HID + 1];
  const int tid = threadIdx.x;
  const int r0 = blockIdx.x * 8;
  for (int i = tid; i < OUTF * HID; i += 256) w2s[i / HID][i % HID] = W2[i];
  for (int i = tid; i < 8 * HID; i += 256)
    hs[i / HID][i % HID] = h2[(size_t)(r0 + i / HID) * HID + (i % HID)];
  __syncthreads();
  for (int oi = tid; oi < 8 * OUTF; oi += 256) {
    const int r = oi / OUTF, o = oi % OUTF;
    const int row = r0 + r, t = row >> 4, b = row & 15;
    float acc = b2[o];
#pragma unroll 8
    for (int k = 0; k < HID; ++k) acc += hs[r][k] * w2s[o][k];
    y[(size_t)row * OUTF + o] = (t < lengths[b]) ? acc : 0.f;
  }
}

extern "C" void kernel_launch(void* const* d_in, const int* in_sizes, int n_in,
                              void* d_out, int out_size, void* d_ws, size_t ws_size,
                              hipStream_t stream) {
  const float* x      = (const float*)d_in[0];
  const int*   lengths= (const int*)d_in[1];
  const float* W1     = (const float*)d_in[2];
  const float* b1     = (const float*)d_in[3];
  const float* Wih    = (const float*)d_in[4];   // [2][1024][256]
  const float* Whh    = (const float*)d_in[5];   // [2][1024][256]
  const float* bih    = (const float*)d_in[6];   // [2][1024]
  const float* bhh    = (const float*)d_in[7];
  const float* W2     = (const float*)d_in[8];
  const float* b2     = (const float*)d_in[9];
  float* out = (float*)d_out;

  char* ws = (char*)d_ws;
  float* h0  = (float*)(ws);                       // 33,554,432 B
  float* gi  = (float*)(ws + 33554432);            // 134,217,728 B (reused by both layers)
  float* h1o = (float*)(ws + 167772160);           // 33,554,432 B
  float* h2o = (float*)(ws + 201326592);           // 33,554,432 B
  float* hx0 = (float*)(ws + 234881024);           // 32,768 B
  float* hx1 = (float*)(ws + 234913792);           // 32,768 B
  unsigned int* cnt0 = (unsigned int*)(ws + 234946560);
  unsigned int* cnt1 = cnt0 + 64;

  // zero exchange buffers + barrier counters (deterministic per launch)
  hipMemsetAsync((void*)hx0, 0, 2 * 32768 + 512, stream);

  inproj<<<2048, 256, 0, stream>>>(x, W1, b1, h0);

  gemm_nt<<<dim3(256, 16), 256, 0, stream>>>(h0, Wih, gi);
  lstm_scan<<<2, 512, 0, stream>>>(gi, Whh, bih, bhh, lengths, h1o, hx0, cnt0);

  gemm_nt<<<dim3(256, 16), 256, 0, stream>>>(h1o, Wih + 262144, gi);
  lstm_scan<<<2, 512, 0, stream>>>(gi, Whh + 262144, bih + 1024, bhh + 1024, lengths, h2o, hx1, cnt1);

  outproj<<<4096, 256, 0, stream>>>(h2o, W2, b2, lengths, out);
}

// Round 2
// 21678.183 us; speedup vs baseline: 1.0999x; 1.0999x over previous
//
#include <hip/hip_runtime.h>
#include <hip/hip_bf16.h>

#define T_STEPS 2048
#define HID 256
#define INF 72
#define OUTF 90

#define VT 46   // weight tiles per wave in VGPRs (46*4 = 184 regs)
#define LT 18   // weight tiles per wave in LDS   (18KB/wave * 8 = 144KB)

typedef __attribute__((ext_vector_type(4))) float f32x4;
typedef __attribute__((ext_vector_type(8))) short s16x8;

__device__ __forceinline__ unsigned short f2bf(float f) {
  union { float f; unsigned u; } v; v.f = f;
  unsigned r = (v.u + 0x7FFFu + ((v.u >> 16) & 1u)) >> 16;   // RNE
  return (unsigned short)r;
}
__device__ __forceinline__ float bf2f(unsigned short s) {
  union { unsigned u; float f; } v; v.u = ((unsigned)s) << 16;
  return v.f;
}
__device__ __forceinline__ float sigm(float x) { return 1.f / (1.f + __expf(-x)); }
__device__ __forceinline__ float tanh_f(float x) { return 1.f - 2.f / (1.f + __expf(2.f * x)); }

// ---------------- input projection: h0 = relu(x @ W1^T + b1) ----------------
__global__ __launch_bounds__(256) void inproj(const float* __restrict__ x,
                                              const float* __restrict__ W1,
                                              const float* __restrict__ b1,
                                              float* __restrict__ h0) {
  __shared__ float w1s[HID][INF + 1];
  __shared__ float xs[16][INF];
  const int tid = threadIdx.x;
  const int r0 = blockIdx.x * 16;
  for (int i = tid; i < HID * INF; i += 256) w1s[i / INF][i % INF] = W1[i];
  for (int i = tid; i < 16 * INF; i += 256)
    xs[i / INF][i % INF] = x[(size_t)(r0 + i / INF) * INF + (i % INF)];
  __syncthreads();
  const float bj = b1[tid];
  for (int r = 0; r < 16; ++r) {
    float acc = bj;
#pragma unroll 8
    for (int k = 0; k < INF; ++k) acc += xs[r][k] * w1s[tid][k];
    h0[(size_t)(r0 + r) * HID + tid] = fmaxf(acc, 0.f);
  }
}

// ------------- gi GEMM: gi = A[32768][256] @ Wih[1024][256]^T + bih + bhh -------------
// Output written as bf16 in MFMA-D-fragment order: [t][w][q][lane][ug*4+r]
__global__ __launch_bounds__(256) void gemm_frag(const float* __restrict__ A,
                                                 const float* __restrict__ B,
                                                 const float* __restrict__ bih,
                                                 const float* __restrict__ bhh,
                                                 unsigned short* __restrict__ gi) {
  const int K = 256;
  __shared__ __align__(16) float As[16][132];
  __shared__ __align__(16) float Bs[16][68];
  const int tid = threadIdx.x;
  const int bm = blockIdx.x, bn = blockIdx.y;
  const int tr = tid >> 4, tc = tid & 15;
  const int arow = tid >> 1, acol = (tid & 1) * 8;
  const int brow = tid >> 2, bcol = (tid & 3) * 4;
  float acc[8][4] = {};
  for (int k0 = 0; k0 < K; k0 += 16) {
    f32x4 av0 = *(const f32x4*)&A[(size_t)(bm * 128 + arow) * K + k0 + acol];
    f32x4 av1 = *(const f32x4*)&A[(size_t)(bm * 128 + arow) * K + k0 + acol + 4];
    f32x4 bv  = *(const f32x4*)&B[(size_t)(bn * 64 + brow) * K + k0 + bcol];
#pragma unroll
    for (int e = 0; e < 4; ++e) {
      As[acol + e][arow] = av0[e];
      As[acol + 4 + e][arow] = av1[e];
      Bs[bcol + e][brow] = bv[e];
    }
    __syncthreads();
#pragma unroll
    for (int kk = 0; kk < 16; ++kk) {
      f32x4 a0 = *(const f32x4*)&As[kk][tr * 8];
      f32x4 a1 = *(const f32x4*)&As[kk][tr * 8 + 4];
      f32x4 b  = *(const f32x4*)&Bs[kk][tc * 4];
#pragma unroll
      for (int i = 0; i < 4; ++i)
#pragma unroll
        for (int jj = 0; jj < 4; ++jj) {
          acc[i][jj]     += a0[i] * b[jj];
          acc[i + 4][jj] += a1[i] * b[jj];
        }
    }
    __syncthreads();
  }
  float bsum[4];
#pragma unroll
  for (int jj = 0; jj < 4; ++jj) {
    const int col = bn * 64 + tc * 4 + jj;
    bsum[jj] = bih[col] + bhh[col];
  }
#pragma unroll
  for (int i = 0; i < 8; ++i)
#pragma unroll
    for (int jj = 0; jj < 4; ++jj) {
      const int row = bm * 128 + tr * 8 + i;
      const int col = bn * 64 + tc * 4 + jj;
      const float v = acc[i][jj] + bsum[jj];
      const int t = row >> 4, b = row & 15;
      const int q = col >> 8, u = col & 255;
      const int wv = u >> 5, ug = (u >> 4) & 1, jl = u & 15;
      const int l = (b >> 2) * 16 + jl, r = b & 3;
      const size_t idx = ((((size_t)t * 8 + wv) * 4 + q) * 64 + l) * 8 + ug * 4 + r;
      gi[idx] = f2bf(v);
    }
}

// ---------------- single-WG LSTM scan: all of Whh on one CU (VGPR + LDS) ----------------
// 8 waves; wave w owns units [32w, 32w+32) (2 unit-tiles), all 4 gates.
// Weight tile tau=(ug*8+kt)*4+q: tau<VT in VGPRs, else in LDS (re-read each step).
// LDS: [0,144K) weight tiles, [144K,160K) h double-buffer (bf16, XOR-swizzled).
__global__ __launch_bounds__(512, 2) void lstm_scan(
    const unsigned short* __restrict__ gi,   // frag bf16 [T][8][4][64][8]
    const float* __restrict__ Whh,           // [1024][256]
    const int* __restrict__ lengths,
    float* __restrict__ hout)                // [T][16][256] masked-zero ys
{
  extern __shared__ char smem[];
  char* hbase = smem + 147456;
  const int tid  = threadIdx.x;
  const int lane = tid & 63;
  const int w    = tid >> 6;
  const int j    = lane & 15;
  const int hi   = lane >> 4;

  // ---- preload weights (f32 -> bf16 fragments) ----
  s16x8 bfrV[VT];
#pragma unroll
  for (int ug = 0; ug < 2; ++ug)
#pragma unroll
    for (int kt = 0; kt < 8; ++kt)
#pragma unroll
      for (int q = 0; q < 4; ++q) {
        const int tau = (ug * 8 + kt) * 4 + q;
        const int u = w * 32 + ug * 16 + j;
        const float* src = Whh + (size_t)(q * 256 + u) * 256 + kt * 32 + hi * 8;
        s16x8 v;
#pragma unroll
        for (int e = 0; e < 8; ++e) v[e] = (short)f2bf(src[e]);
        if (tau < VT) bfrV[tau] = v;
        else *(s16x8*)(smem + (w * LT + (tau - VT)) * 1024 + lane * 16) = v;
      }
  // zero both h buffers
  for (int i = tid; i < 4096; i += 512) ((float*)hbase)[i] = 0.f;
  __syncthreads();

  int len[4];
#pragma unroll
  for (int r = 0; r < 4; ++r) len[r] = lengths[hi * 4 + r];
  float c[8] = {0.f, 0.f, 0.f, 0.f, 0.f, 0.f, 0.f, 0.f};
  unsigned short hprev[8] = {0, 0, 0, 0, 0, 0, 0, 0};

  // gi fragment base for this lane; 4 q-tiles at +q*1024B; step stride 32KB
  const unsigned short* gptr = gi + ((size_t)w * 4 * 64 + lane) * 8;
  s16x8 gfr[4];
#pragma unroll
  for (int q = 0; q < 4; ++q) gfr[q] = *(const s16x8*)(gptr + q * 512);

  for (int t = 0; t < T_STEPS; ++t) {
    const char* hc = hbase + (t & 1) * 8192;
    char* hn = hbase + ((t + 1) & 1) * 8192;
#pragma unroll
    for (int ug = 0; ug < 2; ++ug) {
      f32x4 acc[4];
#pragma unroll
      for (int q = 0; q < 4; ++q)
#pragma unroll
        for (int r = 0; r < 4; ++r)
          acc[q][r] = bf2f((unsigned short)gfr[q][ug * 4 + r]);
      if (ug == 1) {  // gfr dead: prefetch gi[t+1] into the same registers
        const unsigned short* gnx = gptr + (size_t)((t + 1 < T_STEPS) ? t + 1 : t) * 16384;
#pragma unroll
        for (int q = 0; q < 4; ++q) gfr[q] = *(const s16x8*)(gnx + q * 512);
      }
#pragma unroll
      for (int kt = 0; kt < 8; ++kt) {
        const int k = kt * 32 + hi * 8;
        const int koff = ((j << 9) + (k << 1)) ^ ((j & 7) << 4);
        const s16x8 a = *(const s16x8*)(hc + koff);
#pragma unroll
        for (int q = 0; q < 4; ++q) {
          const int tau = (ug * 8 + kt) * 4 + q;
          s16x8 bw;
          if (tau < VT) bw = bfrV[tau];
          else bw = *(const s16x8*)(smem + (w * LT + (tau - VT)) * 1024 + lane * 16);
          acc[q] = __builtin_amdgcn_mfma_f32_16x16x32_bf16(a, bw, acc[q], 0, 0, 0);
        }
      }
      const int u = w * 32 + ug * 16 + j;
#pragma unroll
      for (int r = 0; r < 4; ++r) {
        const int ci = ug * 4 + r;
        const float i_ = sigm(acc[0][r]);
        const float f_ = sigm(acc[1][r]);
        const float tg = tanh_f(acc[2][r]);
        const float o_ = sigm(acc[3][r]);
        const float cn = f_ * c[ci] + i_ * tg;
        const float hv = o_ * tanh_f(cn);
        const bool m = t < len[r];
        c[ci] = m ? cn : c[ci];
        const unsigned short hb = m ? f2bf(hv) : hprev[ci];
        hprev[ci] = hb;
        const int b = hi * 4 + r;
        const int hoff = ((b << 9) + (u << 1)) ^ ((b & 7) << 4);
        *(unsigned short*)(hn + hoff) = hb;
        hout[((size_t)t * 16 + b) * HID + u] = m ? hv : 0.f;
      }
    }
    __syncthreads();
  }
}

// ---------------- output projection: y = mask ? h2 @ W2^T + b2 : 0 ----------------
__global__ __launch_bounds__(256) void outproj(const float* __restrict__ h2,
                                               const float* __restrict__ W2,
                                               const float* __restrict__ b2,
                                               const int* __restrict__ lengths,
                                               float* __restrict__ y) {
  __shared__ float w2s[OUTF][HID + 1];
  __shared__ float hs[8][HID + 1];
  const int tid = threadIdx.x;
  const int r0 = blockIdx.x * 8;
  for (int i = tid; i < OUTF * HID; i += 256) w2s[i / HID][i % HID] = W2[i];
  for (int i = tid; i < 8 * HID; i += 256)
    hs[i / HID][i % HID] = h2[(size_t)(r0 + i / HID) * HID + (i % HID)];
  __syncthreads();
  for (int oi = tid; oi < 8 * OUTF; oi += 256) {
    const int r = oi / OUTF, o = oi % OUTF;
    const int row = r0 + r, t = row >> 4, b = row & 15;
    float acc = b2[o];
#pragma unroll 8
    for (int k = 0; k < HID; ++k) acc += hs[r][k] * w2s[o][k];
    y[(size_t)row * OUTF + o] = (t < lengths[b]) ? acc : 0.f;
  }
}

extern "C" void kernel_launch(void* const* d_in, const int* in_sizes, int n_in,
                              void* d_out, int out_size, void* d_ws, size_t ws_size,
                              hipStream_t stream) {
  const float* x      = (const float*)d_in[0];
  const int*   lengths= (const int*)d_in[1];
  const float* W1     = (const float*)d_in[2];
  const float* b1     = (const float*)d_in[3];
  const float* Wih    = (const float*)d_in[4];   // [2][1024][256]
  const float* Whh    = (const float*)d_in[5];   // [2][1024][256]
  const float* bih    = (const float*)d_in[6];   // [2][1024]
  const float* bhh    = (const float*)d_in[7];
  const float* W2     = (const float*)d_in[8];
  const float* b2     = (const float*)d_in[9];
  float* out = (float*)d_out;

  char* ws = (char*)d_ws;
  float*          h0 = (float*)(ws);                         // 33,554,432 B
  unsigned short* gf = (unsigned short*)(ws + 33554432);     // 67,108,864 B (bf16 gi frags)
  float*          h1 = (float*)(ws + 100663296);             // 33,554,432 B
  float*          h2 = (float*)(ws + 134217728);             // 33,554,432 B

  hipFuncSetAttribute((const void*)lstm_scan,
                      hipFuncAttributeMaxDynamicSharedMemorySize, 163840);

  inproj<<<2048, 256, 0, stream>>>(x, W1, b1, h0);

  gemm_frag<<<dim3(256, 16), 256, 0, stream>>>(h0, Wih, bih, bhh, gf);
  lstm_scan<<<1, 512, 163840, stream>>>(gf, Whh, lengths, h1);

  gemm_frag<<<dim3(256, 16), 256, 0, stream>>>(h1, Wih + 262144, bih + 1024, bhh + 1024, gf);
  lstm_scan<<<1, 512, 163840, stream>>>(gf, Whh + 262144, lengths, h2);

  outproj<<<4096, 256, 0, stream>>>(h2, W2, b2, lengths, out);
}